// Round 1
// baseline (374.796 us; speedup 1.0000x reference)
//
#include <hip/hip_runtime.h>

#define N_F 64
#define L_H 96
#define L_P 24
#define L_ALL 120
#define H_DIM 128
#define B_SZ 1024

typedef _Float16 f16x8 __attribute__((ext_vector_type(8)));
typedef float f32x4 __attribute__((ext_vector_type(4)));

__device__ __forceinline__ float fast_sigmoid(float x) {
    return 1.0f / (1.0f + __expf(-x));
}
__device__ __forceinline__ float fast_tanh(float x) {
    x = fminf(fmaxf(x, -15.0f), 15.0f);
    float e = __expf(2.0f * x);
    return (e - 1.0f) / (e + 1.0f);
}

// One block = 16 batch rows, 512 threads = 8 waves.
// Wave w owns hidden cols hc in [16w, 16w+16). Its 4 MFMA tiles (r, z, gin, grn)
// all produce the SAME col range -> the GRU elementwise update is fully
// in-register (no LDS round trip for gates). h master copy: fp32, 4 regs/lane
// (rows quad*4+r, col hc), matching the MFMA C/D layout (col=lane&15,
// row=(lane>>4)*4+reg).
__global__ __launch_bounds__(512, 2) void grud_kernel(
    const float* __restrict__ tp_pred, const float* __restrict__ X,
    const float* __restrict__ tp_true, const float* __restrict__ mask,
    const float* __restrict__ Wh_dec, const float* __restrict__ bh_dec,
    const float* __restrict__ Wx_dec, const float* __restrict__ bx_dec,
    const float* __restrict__ W_ih, const float* __restrict__ W_hh,
    const float* __restrict__ b_ih, const float* __restrict__ b_hh,
    const float* __restrict__ Wp, const float* __restrict__ bp,
    float* __restrict__ out)
{
    constexpr int VROW = 264;  // 256 + 8 halfs pad -> A-frag b128 reads conflict-free
    __shared__ alignas(16) _Float16 V[16 * VROW];     // [row][k]: x_in(0..63) m(64..127) h(128..255)
    __shared__ alignas(16) float dt_lds[L_ALL * 16];  // [t][row]

    const int tid  = threadIdx.x;
    const int w    = tid >> 6;   // wave 0..7
    const int l    = tid & 63;
    const int quad = l >> 4;
    const int lm   = l & 15;
    const int b0   = blockIdx.x * 16;

    // ---- dt precompute into LDS ----
    for (int idx = tid; idx < L_ALL * 16; idx += 512) {
        int t = idx >> 4, i = idx & 15;
        int b = b0 + i;
        float v = 0.0f;
        if (t != 0) {
            float cur = (t < L_H) ? tp_true[b * L_H + t] : tp_pred[b * L_P + (t - L_H)];
            float prv = ((t - 1) < L_H) ? tp_true[b * L_H + (t - 1)]
                                        : tp_pred[b * L_P + (t - 1 - L_H)];
            v = cur - prv;
        }
        dt_lds[t * 16 + i] = v;
    }

    // ---- u-hat: lane handles feature col n=l for rows {w, w+8} ----
    const int un = l;
    const int i0 = w, i1 = w + 8;
    const float wxd = Wx_dec[un * N_F + un];
    const float bxn = bx_dec[un];
    float mu0, mu1;
    {
        const float* xr0 = X    + (size_t)(b0 + i0) * L_H * N_F + un;
        const float* mr0 = mask + (size_t)(b0 + i0) * L_H * N_F + un;
        const float* xr1 = X    + (size_t)(b0 + i1) * L_H * N_F + un;
        const float* mr1 = mask + (size_t)(b0 + i1) * L_H * N_F + un;
        float a0 = 0, c0 = 0, a1 = 0, c1 = 0;
        for (int t = 0; t < L_H; ++t) {
            float x0 = xr0[t * N_F], m0 = mr0[t * N_F];
            float x1 = xr1[t * N_F], m1 = mr1[t * N_F];
            a0 += x0 * (1.0f - m0); c0 += (1.0f - m0);
            a1 += x1 * (1.0f - m1); c1 += (1.0f - m1);
        }
        // cnt = 24 (pred window, all "valid") + sum(1-m); always >= 24 so no clip
        mu0 = a0 / (c0 + (float)L_P);
        mu1 = a1 / (c1 + (float)L_P);
    }

    // ---- gate-hat consts ----
    const int hc = w * 16 + lm;
    float S = 0.0f;
    for (int nn = 0; nn < N_F; ++nn) S += Wh_dec[hc * N_F + nn];  // d_t@Wh_dec.T = dt*rowsum
    const float bhv = bh_dec[hc];
    const float bR  = b_ih[hc] + b_hh[hc];
    const float bZ  = b_ih[H_DIM + hc] + b_hh[H_DIM + hc];
    const float bN  = b_ih[2 * H_DIM + hc];
    const float bG  = b_hh[2 * H_DIM + hc];

    // ---- weight B-fragments (registers, persistent across all 120 steps) ----
    // B-frag layout: lane holds B[k = 32*fi + quad*8 + q][col = tile_base + lm]
    // Unified K: k<64 -> x_in part (W_ih[:, :64]); 64<=k<128 -> m part (W_ih[:, 192:]);
    //            k>=128 -> h part (W_ih[:, 64:192] (+W_hh for r,z)).
    f16x8 wR[8], wZ[8], wN[8], wG[4];
#pragma unroll
    for (int fi = 0; fi < 8; ++fi) {
#pragma unroll
        for (int q = 0; q < 8; ++q) {
            const int kk = fi * 32 + quad * 8 + q;
            const int jr = hc, jz = H_DIM + hc, jn = 2 * H_DIM + hc;
            float vR, vZ, vN;
            if (kk < 64) {
                vR = W_ih[jr * 256 + kk];
                vZ = W_ih[jz * 256 + kk];
                vN = W_ih[jn * 256 + kk];
            } else if (kk < 128) {
                vR = W_ih[jr * 256 + 192 + (kk - 64)];
                vZ = W_ih[jz * 256 + 192 + (kk - 64)];
                vN = W_ih[jn * 256 + 192 + (kk - 64)];
            } else {
                const int c = kk - 128;
                vR = W_ih[jr * 256 + 64 + c] + W_hh[jr * 128 + c];
                vZ = W_ih[jz * 256 + 64 + c] + W_hh[jz * 128 + c];
                vN = W_ih[jn * 256 + 64 + c];
                wG[fi - 4][q] = (_Float16)W_hh[jn * 128 + c];
            }
            wR[fi][q] = (_Float16)vR;
            wZ[fi][q] = (_Float16)vZ;
            wN[fi][q] = (_Float16)vN;
        }
    }

    // ---- projection (waves 0..3 own 16 output cols each; K=128 over h) ----
    f16x8 wP[4];
    float bpv = 0.0f;
    const int pn = (w & 3) * 16 + lm;
    if (w < 4) {
        bpv = bp[pn];
#pragma unroll
        for (int p = 0; p < 4; ++p)
#pragma unroll
            for (int q = 0; q < 8; ++q)
                wP[p][q] = (_Float16)Wp[pn * H_DIM + (p * 32 + quad * 8 + q)];
    }

    float h[4] = {0.0f, 0.0f, 0.0f, 0.0f};

    __syncthreads();

    for (int t = 0; t < L_ALL; ++t) {
        // ---- Phase A: build V = [x_in, m, h*gh] (fp16) ----
        {
            const float d0 = dt_lds[t * 16 + i0];
            const float d1 = dt_lds[t * 16 + i1];
            float x0 = 0, m0 = 0, x1 = 0, m1 = 0;
            if (t < L_H) {
                const size_t off0 = (size_t)(b0 + i0) * L_H * N_F + (size_t)t * N_F + un;
                const size_t off1 = (size_t)(b0 + i1) * L_H * N_F + (size_t)t * N_F + un;
                x0 = X[off0]; m0 = mask[off0];
                x1 = X[off1]; m1 = mask[off1];
            }
            const float gx0 = __expf(-fmaxf(d0 * wxd + bxn, 0.0f));
            const float gx1 = __expf(-fmaxf(d1 * wxd + bxn, 0.0f));
            // LOCF collapse: when m==0, X_locf[t]==x_t; when m==1, x_in==x_t.
            const float xi0 = (m0 != 0.0f) ? x0 : (gx0 * x0 + (1.0f - gx0) * mu0);
            const float xi1 = (m1 != 0.0f) ? x1 : (gx1 * x1 + (1.0f - gx1) * mu1);
            V[i0 * VROW + un]       = (_Float16)xi0;
            V[i0 * VROW + 64 + un]  = (_Float16)m0;
            V[i1 * VROW + un]       = (_Float16)xi1;
            V[i1 * VROW + 64 + un]  = (_Float16)m1;

            const float4 dtv = *(const float4*)&dt_lds[t * 16 + quad * 4];
            const float dts[4] = {dtv.x, dtv.y, dtv.z, dtv.w};
#pragma unroll
            for (int r = 0; r < 4; ++r) {
                const float gh = __expf(-fmaxf(dts[r] * S + bhv, 0.0f));
                h[r] *= gh;  // h_pre == rep for this step
                V[(quad * 4 + r) * VROW + H_DIM + hc] = (_Float16)h[r];
            }
        }
        __syncthreads();

        // ---- Phase B: A-fragments (lane: V[row=lm][k = 32*fi + quad*8 + 0..7]) ----
        f16x8 af[8];
#pragma unroll
        for (int fi = 0; fi < 8; ++fi)
            af[fi] = *(const f16x8*)&V[lm * VROW + fi * 32 + quad * 8];
        __syncthreads();

        // ---- Phase C: MFMAs + in-register GRU update ----
        f32x4 aR = {0,0,0,0}, aZ = {0,0,0,0}, aN = {0,0,0,0}, aG = {0,0,0,0};
#pragma unroll
        for (int fi = 0; fi < 8; ++fi) {
            aR = __builtin_amdgcn_mfma_f32_16x16x32_f16(af[fi], wR[fi], aR, 0, 0, 0);
            aZ = __builtin_amdgcn_mfma_f32_16x16x32_f16(af[fi], wZ[fi], aZ, 0, 0, 0);
            aN = __builtin_amdgcn_mfma_f32_16x16x32_f16(af[fi], wN[fi], aN, 0, 0, 0);
        }
#pragma unroll
        for (int p = 0; p < 4; ++p)
            aG = __builtin_amdgcn_mfma_f32_16x16x32_f16(af[4 + p], wG[p], aG, 0, 0, 0);

#pragma unroll
        for (int r = 0; r < 4; ++r) {
            const float rg = fast_sigmoid(aR[r] + bR);
            const float zg = fast_sigmoid(aZ[r] + bZ);
            const float ng = fast_tanh(aN[r] + bN + rg * (aG[r] + bG));
            h[r] = (1.0f - zg) * ng + zg * h[r];
        }

        // ---- projection of rep (= decayed h already in af[4..7]) for t>=96 ----
        if (t >= L_H && w < 4) {
            f32x4 aP = {0,0,0,0};
#pragma unroll
            for (int p = 0; p < 4; ++p)
                aP = __builtin_amdgcn_mfma_f32_16x16x32_f16(af[4 + p], wP[p], aP, 0, 0, 0);
#pragma unroll
            for (int r = 0; r < 4; ++r) {
                const int row = quad * 4 + r;
                out[((size_t)(b0 + row) * L_P + (t - L_H)) * N_F + pn] = aP[r] + bpv;
            }
        }
    }
}

extern "C" void kernel_launch(void* const* d_in, const int* in_sizes, int n_in,
                              void* d_out, int out_size, void* d_ws, size_t ws_size,
                              hipStream_t stream) {
    const float* tp_pred = (const float*)d_in[0];
    const float* X       = (const float*)d_in[1];
    const float* tp_true = (const float*)d_in[2];
    const float* mask    = (const float*)d_in[3];
    const float* Wh_dec  = (const float*)d_in[4];
    const float* bh_dec  = (const float*)d_in[5];
    const float* Wx_dec  = (const float*)d_in[6];
    const float* bx_dec  = (const float*)d_in[7];
    const float* W_ih    = (const float*)d_in[8];
    const float* W_hh    = (const float*)d_in[9];
    const float* b_ih    = (const float*)d_in[10];
    const float* b_hh    = (const float*)d_in[11];
    const float* Wp      = (const float*)d_in[12];
    const float* bp      = (const float*)d_in[13];

    grud_kernel<<<dim3(B_SZ / 16), dim3(512), 0, stream>>>(
        tp_pred, X, tp_true, mask, Wh_dec, bh_dec, Wx_dec, bx_dec,
        W_ih, W_hh, b_ih, b_hh, Wp, bp, (float*)d_out);
}

// Round 2
// 339.763 us; speedup vs baseline: 1.1031x; 1.1031x over previous
//
#include <hip/hip_runtime.h>

#define N_F 64
#define L_H 96
#define L_P 24
#define L_ALL 120
#define H_DIM 128
#define B_SZ 1024

typedef _Float16 f16x8 __attribute__((ext_vector_type(8)));
typedef float f32x4 __attribute__((ext_vector_type(4)));

__device__ __forceinline__ float fast_sigmoid(float x) {
    return 1.0f / (1.0f + __expf(-x));
}
__device__ __forceinline__ float fast_tanh(float x) {
    x = fminf(fmaxf(x, -15.0f), 15.0f);
    float e = __expf(2.0f * x);
    return (e - 1.0f) / (e + 1.0f);
}

// LDS-only barrier: orders LDS writes/reads across waves WITHOUT draining
// vmcnt (global prefetch loads / projection stores stay in flight).
// __syncthreads() would emit s_waitcnt vmcnt(0) lgkmcnt(0) — the per-step
// drain was the R1 bottleneck (2.37 us/step, all pipes <12% busy).
__device__ __forceinline__ void barrier_lds_only() {
    __asm__ volatile("s_waitcnt lgkmcnt(0)\n\ts_barrier" ::: "memory");
}

// One block = 16 batch rows, 8 waves. Wave w owns hidden cols [16w,16w+16);
// r/z/n-in/n-rec tiles for those cols -> GRU update fully in-register.
// h master fp32 in C/D layout (col=lane&15, row=quad*4+reg).
// Double-buffered V + raw lgkm-barrier: ONE barrier/step, no vm drain.
__global__ __launch_bounds__(512, 2) void grud_kernel(
    const float* __restrict__ tp_pred, const float* __restrict__ X,
    const float* __restrict__ tp_true, const float* __restrict__ mask,
    const float* __restrict__ Wh_dec, const float* __restrict__ bh_dec,
    const float* __restrict__ Wx_dec, const float* __restrict__ bx_dec,
    const float* __restrict__ W_ih, const float* __restrict__ W_hh,
    const float* __restrict__ b_ih, const float* __restrict__ b_hh,
    const float* __restrict__ Wp, const float* __restrict__ bp,
    float* __restrict__ out)
{
    constexpr int VROW = 264;  // 256 + 8 halfs pad
    __shared__ alignas(16) _Float16 V[2][16 * VROW];  // [buf][row][k]: x_in | m | h_dec
    __shared__ alignas(16) float dt_lds[L_ALL * 16];  // [t][row]

    const int tid  = threadIdx.x;
    const int w    = tid >> 6;
    const int l    = tid & 63;
    const int quad = l >> 4;
    const int lm   = l & 15;
    const int b0   = blockIdx.x * 16;

    // ---- dt precompute into LDS ----
    for (int idx = tid; idx < L_ALL * 16; idx += 512) {
        int t = idx >> 4, i = idx & 15;
        int b = b0 + i;
        float v = 0.0f;
        if (t != 0) {
            float cur = (t < L_H) ? tp_true[b * L_H + t] : tp_pred[b * L_P + (t - L_H)];
            float prv = ((t - 1) < L_H) ? tp_true[b * L_H + (t - 1)]
                                        : tp_pred[b * L_P + (t - 1 - L_H)];
            v = cur - prv;
        }
        dt_lds[t * 16 + i] = v;
    }

    // ---- mu: lane handles feature col n=l for rows {w, w+8} ----
    const int un = l;
    const int i0 = w, i1 = w + 8;
    const float wxd = Wx_dec[un * N_F + un];
    const float bxn = bx_dec[un];
    float mu0, mu1;
    {
        const float* xr0 = X    + (size_t)(b0 + i0) * L_H * N_F + un;
        const float* mr0 = mask + (size_t)(b0 + i0) * L_H * N_F + un;
        const float* xr1 = X    + (size_t)(b0 + i1) * L_H * N_F + un;
        const float* mr1 = mask + (size_t)(b0 + i1) * L_H * N_F + un;
        float a0 = 0, c0 = 0, a1 = 0, c1 = 0;
        for (int t = 0; t < L_H; ++t) {
            float x0 = xr0[t * N_F], m0 = mr0[t * N_F];
            float x1 = xr1[t * N_F], m1 = mr1[t * N_F];
            a0 += x0 * (1.0f - m0); c0 += (1.0f - m0);
            a1 += x1 * (1.0f - m1); c1 += (1.0f - m1);
        }
        // cnt = 24 (pred window zeros count as valid) + sum(1-m) >= 24, no clip
        mu0 = a0 / (c0 + (float)L_P);
        mu1 = a1 / (c1 + (float)L_P);
    }

    // ---- gate consts ----
    const int hc = w * 16 + lm;
    float S = 0.0f;
    for (int nn = 0; nn < N_F; ++nn) S += Wh_dec[hc * N_F + nn];  // dt@Wh_dec.T = dt*rowsum
    const float bhv = bh_dec[hc];
    const float bR  = b_ih[hc] + b_hh[hc];
    const float bZ  = b_ih[H_DIM + hc] + b_hh[H_DIM + hc];
    const float bN  = b_ih[2 * H_DIM + hc];
    const float bG  = b_hh[2 * H_DIM + hc];

    // ---- weight B-fragments (persistent registers) ----
    // k<64 -> x_in (W_ih[:, :64]); 64<=k<128 -> m (W_ih[:, 192:]);
    // k>=128 -> h (W_ih[:, 64:192], +W_hh for r,z).
    f16x8 wR[8], wZ[8], wN[8], wG[4];
#pragma unroll
    for (int fi = 0; fi < 8; ++fi) {
#pragma unroll
        for (int q = 0; q < 8; ++q) {
            const int kk = fi * 32 + quad * 8 + q;
            const int jr = hc, jz = H_DIM + hc, jn = 2 * H_DIM + hc;
            float vR, vZ, vN;
            if (kk < 64) {
                vR = W_ih[jr * 256 + kk];
                vZ = W_ih[jz * 256 + kk];
                vN = W_ih[jn * 256 + kk];
            } else if (kk < 128) {
                vR = W_ih[jr * 256 + 192 + (kk - 64)];
                vZ = W_ih[jz * 256 + 192 + (kk - 64)];
                vN = W_ih[jn * 256 + 192 + (kk - 64)];
            } else {
                const int c = kk - 128;
                vR = W_ih[jr * 256 + 64 + c] + W_hh[jr * 128 + c];
                vZ = W_ih[jz * 256 + 64 + c] + W_hh[jz * 128 + c];
                vN = W_ih[jn * 256 + 64 + c];
                wG[fi - 4][q] = (_Float16)W_hh[jn * 128 + c];
            }
            wR[fi][q] = (_Float16)vR;
            wZ[fi][q] = (_Float16)vZ;
            wN[fi][q] = (_Float16)vN;
        }
    }

    // ---- projection weights (waves 0..3, 16 out cols each) ----
    f16x8 wP[4];
    float bpv = 0.0f;
    const int pn = (w & 3) * 16 + lm;
    if (w < 4) {
        bpv = bp[pn];
#pragma unroll
        for (int p = 0; p < 4; ++p)
#pragma unroll
            for (int q = 0; q < 8; ++q)
                wP[p][q] = (_Float16)Wp[pn * H_DIM + (p * 32 + quad * 8 + q)];
    }

    // ---- init V[0] for t=0 (dt=0; h=0) ----
    {
        const size_t o0 = (size_t)(b0 + i0) * L_H * N_F + un;
        const size_t o1 = (size_t)(b0 + i1) * L_H * N_F + un;
        float x0 = X[o0], m0 = mask[o0];
        float x1 = X[o1], m1 = mask[o1];
        const float gx = __expf(-fmaxf(bxn, 0.0f));
        float xi0 = (m0 != 0.0f) ? x0 : (gx * x0 + (1.0f - gx) * mu0);
        float xi1 = (m1 != 0.0f) ? x1 : (gx * x1 + (1.0f - gx) * mu1);
        V[0][i0 * VROW + un]      = (_Float16)xi0;
        V[0][i0 * VROW + 64 + un] = (_Float16)m0;
        V[0][i1 * VROW + un]      = (_Float16)xi1;
        V[0][i1 * VROW + 64 + un] = (_Float16)m1;
#pragma unroll
        for (int r = 0; r < 4; ++r)
            V[0][(quad * 4 + r) * VROW + H_DIM + hc] = (_Float16)0.0f;
    }

    float h[4] = {0.0f, 0.0f, 0.0f, 0.0f};

    __syncthreads();  // one full barrier after setup (covers dt_lds + V[0])

    // prefetch register sets (distance-2 pipeline via unroll-2)
    auto ldxm = [&](int t, float& px0, float& pm0, float& px1, float& pm1) {
        if (t < L_H) {
            const size_t o0 = (size_t)(b0 + i0) * L_H * N_F + (size_t)t * N_F + un;
            const size_t o1 = (size_t)(b0 + i1) * L_H * N_F + (size_t)t * N_F + un;
            px0 = X[o0]; pm0 = mask[o0];
            px1 = X[o1]; pm1 = mask[o1];
        } else {
            px0 = 0.0f; pm0 = 0.0f; px1 = 0.0f; pm1 = 0.0f;
        }
    };

    auto body = [&](int t, float cx0, float cm0, float cx1, float cm1,
                    float& fx0, float& fm0, float& fx1, float& fm1) {
        const int p = t & 1;

        // A-fragments from V[p]
        f16x8 af[8];
#pragma unroll
        for (int fi = 0; fi < 8; ++fi)
            af[fi] = *(const f16x8*)&V[p][lm * VROW + fi * 32 + quad * 8];

        // issue global prefetch for step t+3 (consumed 2 iterations from now)
        ldxm(t + 3, fx0, fm0, fx1, fm1);

        // MFMA phase
        f32x4 aR = {0,0,0,0}, aZ = {0,0,0,0}, aN = {0,0,0,0}, aG = {0,0,0,0};
#pragma unroll
        for (int fi = 0; fi < 8; ++fi) {
            aR = __builtin_amdgcn_mfma_f32_16x16x32_f16(af[fi], wR[fi], aR, 0, 0, 0);
            aZ = __builtin_amdgcn_mfma_f32_16x16x32_f16(af[fi], wZ[fi], aZ, 0, 0, 0);
            aN = __builtin_amdgcn_mfma_f32_16x16x32_f16(af[fi], wN[fi], aN, 0, 0, 0);
        }
#pragma unroll
        for (int p4 = 0; p4 < 4; ++p4)
            aG = __builtin_amdgcn_mfma_f32_16x16x32_f16(af[4 + p4], wG[p4], aG, 0, 0, 0);

        // projection of rep_t (= af[4..7]) for tail steps; stores NOT drained
        // at the barrier (raw lgkm-barrier), so they leave the critical path.
        if (t >= L_H && w < 4) {
            f32x4 aP = {0,0,0,0};
#pragma unroll
            for (int p4 = 0; p4 < 4; ++p4)
                aP = __builtin_amdgcn_mfma_f32_16x16x32_f16(af[4 + p4], wP[p4], aP, 0, 0, 0);
#pragma unroll
            for (int r = 0; r < 4; ++r) {
                const int row = quad * 4 + r;
                out[((size_t)(b0 + row) * L_P + (t - L_H)) * N_F + pn] = aP[r] + bpv;
            }
        }

        // build V[p^1] x/m-part for step t+1 (independent of h -> off chain)
        float ghn[4];
        if (t < L_ALL - 1) {
            const float d0 = dt_lds[(t + 1) * 16 + i0];
            const float d1 = dt_lds[(t + 1) * 16 + i1];
            const float gx0 = __expf(-fmaxf(d0 * wxd + bxn, 0.0f));
            const float gx1 = __expf(-fmaxf(d1 * wxd + bxn, 0.0f));
            const float xi0 = (cm0 != 0.0f) ? cx0 : (gx0 * cx0 + (1.0f - gx0) * mu0);
            const float xi1 = (cm1 != 0.0f) ? cx1 : (gx1 * cx1 + (1.0f - gx1) * mu1);
            V[p ^ 1][i0 * VROW + un]      = (_Float16)xi0;
            V[p ^ 1][i0 * VROW + 64 + un] = (_Float16)cm0;
            V[p ^ 1][i1 * VROW + un]      = (_Float16)xi1;
            V[p ^ 1][i1 * VROW + 64 + un] = (_Float16)cm1;

            // gh for t+1 precomputed off the MFMA->gate chain
            const float4 dtv = *(const float4*)&dt_lds[(t + 1) * 16 + quad * 4];
            const float dts[4] = {dtv.x, dtv.y, dtv.z, dtv.w};
#pragma unroll
            for (int r = 0; r < 4; ++r)
                ghn[r] = __expf(-fmaxf(dts[r] * S + bhv, 0.0f));
        }

        // gates + h update (critical chain: MFMA -> 2 dep exps -> fma -> LDS write)
#pragma unroll
        for (int r = 0; r < 4; ++r) {
            const float rg = fast_sigmoid(aR[r] + bR);
            const float zg = fast_sigmoid(aZ[r] + bZ);
            const float ng = fast_tanh(aN[r] + bN + rg * (aG[r] + bG));
            h[r] = (1.0f - zg) * ng + zg * h[r];
        }
        if (t < L_ALL - 1) {
#pragma unroll
            for (int r = 0; r < 4; ++r) {
                h[r] *= ghn[r];  // decayed h = rep_{t+1}
                V[p ^ 1][(quad * 4 + r) * VROW + H_DIM + hc] = (_Float16)h[r];
            }
        }

        barrier_lds_only();
    };

    float aX0, aM0, aX1, aM1, bX0, bM0, bX1, bM1;
    ldxm(1, aX0, aM0, aX1, aM1);
    ldxm(2, bX0, bM0, bX1, bM1);

    for (int t = 0; t < L_ALL; t += 2) {
        body(t,     aX0, aM0, aX1, aM1, aX0, aM0, aX1, aM1);
        body(t + 1, bX0, bM0, bX1, bM1, bX0, bM0, bX1, bM1);
    }
}

extern "C" void kernel_launch(void* const* d_in, const int* in_sizes, int n_in,
                              void* d_out, int out_size, void* d_ws, size_t ws_size,
                              hipStream_t stream) {
    const float* tp_pred = (const float*)d_in[0];
    const float* X       = (const float*)d_in[1];
    const float* tp_true = (const float*)d_in[2];
    const float* mask    = (const float*)d_in[3];
    const float* Wh_dec  = (const float*)d_in[4];
    const float* bh_dec  = (const float*)d_in[5];
    const float* Wx_dec  = (const float*)d_in[6];
    const float* bx_dec  = (const float*)d_in[7];
    const float* W_ih    = (const float*)d_in[8];
    const float* W_hh    = (const float*)d_in[9];
    const float* b_ih    = (const float*)d_in[10];
    const float* b_hh    = (const float*)d_in[11];
    const float* Wp      = (const float*)d_in[12];
    const float* bp      = (const float*)d_in[13];

    grud_kernel<<<dim3(B_SZ / 16), dim3(512), 0, stream>>>(
        tp_pred, X, tp_true, mask, Wh_dec, bh_dec, Wx_dec, bx_dec,
        W_ih, W_hh, b_ih, b_hh, Wp, bp, (float*)d_out);
}

// Round 3
// 243.569 us; speedup vs baseline: 1.5388x; 1.3949x over previous
//
#include <hip/hip_runtime.h>

#define N_F 64
#define L_H 96
#define L_P 24
#define L_ALL 120
#define H_DIM 128
#define B_SZ 1024
#define LOG2E 1.4426950408889634f

typedef _Float16 f16x8 __attribute__((ext_vector_type(8)));
typedef float f32x4 __attribute__((ext_vector_type(4)));

// sigmoid = rcp(1+exp2(-x*log2e)) : 4 VALU (vs ~25 with IEEE div + __expf)
__device__ __forceinline__ float sig_fast(float x) {
    return __builtin_amdgcn_rcpf(1.0f + __builtin_amdgcn_exp2f(-LOG2E * x));
}
// tanh = 1 - 2*rcp(1+exp2(2*log2e*x)); exp2 inf/0 semantics give exact +-1 tails
__device__ __forceinline__ float tanh_fast(float x) {
    return 1.0f - 2.0f * __builtin_amdgcn_rcpf(1.0f + __builtin_amdgcn_exp2f(2.0f * LOG2E * x));
}
// exp(-relu(x))
__device__ __forceinline__ float expnr_fast(float x) {
    return __builtin_amdgcn_exp2f(-LOG2E * fmaxf(x, 0.0f));
}

// LDS-only barrier: global loads/stores stay in flight across it.
__device__ __forceinline__ void barrier_lds_only() {
    __asm__ volatile("s_waitcnt lgkmcnt(0)\n\ts_barrier" ::: "memory");
}

struct F8 { float v[8]; };
__device__ __forceinline__ F8 ld8(const float* p) {
    F8 r;
    float4 a = *(const float4*)p;
    float4 b = *(const float4*)(p + 4);
    r.v[0]=a.x; r.v[1]=a.y; r.v[2]=a.z; r.v[3]=a.w;
    r.v[4]=b.x; r.v[5]=b.y; r.v[6]=b.z; r.v[7]=b.w;
    return r;
}

// 256 blocks x 4 batch rows (MFMA tile rows {0,4,8,12} -> C/D reg 0 only),
// 8 waves. Wave w owns hidden cols [16w,16w+16) for r/z/n_in/n_rec -> GRU
// update fully in-register, ONE gate triple per lane. Waves 0-3 stage x/m,
// waves 4-7 do the tail projection. Double-buffered V + lgkm-only barrier.
__global__ __launch_bounds__(512, 2) void grud_kernel(
    const float* __restrict__ tp_pred, const float* __restrict__ X,
    const float* __restrict__ tp_true, const float* __restrict__ mask,
    const float* __restrict__ Wh_dec, const float* __restrict__ bh_dec,
    const float* __restrict__ Wx_dec, const float* __restrict__ bx_dec,
    const float* __restrict__ W_ih, const float* __restrict__ W_hh,
    const float* __restrict__ b_ih, const float* __restrict__ b_hh,
    const float* __restrict__ Wp, const float* __restrict__ bp,
    float* __restrict__ out)
{
    constexpr int VROW = 264;  // 256 + 8 halfs pad
    __shared__ alignas(16) _Float16 V[2][16 * VROW];  // [buf][row][k]: x_in | m | h_dec
    __shared__ float dt_lds[L_ALL * 4];               // [t][q]
    __shared__ float muA[8][64], muC[8][64];

    const int tid  = threadIdx.x;
    const int w    = tid >> 6;
    const int l    = tid & 63;
    const int quad = l >> 4;
    const int lm   = l & 15;
    const int b0   = blockIdx.x * 4;

    // ---- zero both V buffers (invalid tile rows must stay 0 forever) ----
    for (int idx = tid; idx < 16 * VROW; idx += 512)   // 2*16*VROW halfs = 16*VROW uints
        ((unsigned int*)V)[idx] = 0;

    // ---- dt into LDS: [t][q] ----
    for (int idx = tid; idx < L_ALL * 4; idx += 512) {
        int t = idx >> 2, q = idx & 3;
        int b = b0 + q;
        float v = 0.0f;
        if (t != 0) {
            float cur = (t < L_H) ? tp_true[b * L_H + t] : tp_pred[b * L_P + (t - L_H)];
            float prv = ((t - 1) < L_H) ? tp_true[b * L_H + (t - 1)]
                                        : tp_pred[b * L_P + (t - 1 - L_H)];
            v = cur - prv;
        }
        dt_lds[idx] = v;
    }

    // ---- mu partials: wave w handles row (w&3), time-half (w>>2) ----
    {
        const int q = w & 3, half = w >> 2;
        const float* xr = X    + (size_t)(b0 + q) * L_H * N_F + l;
        const float* mr = mask + (size_t)(b0 + q) * L_H * N_F + l;
        float a = 0.0f, c = 0.0f;
        for (int t = half * 48; t < half * 48 + 48; ++t) {
            float x = xr[(size_t)t * N_F], m = mr[(size_t)t * N_F];
            a += x * (1.0f - m); c += 1.0f - m;
        }
        muA[w][l] = a; muC[w][l] = c;
    }
    __syncthreads();

    float muv = 0.0f;
    if (w < 4)  // cnt = 24 (pred window) + sum(1-m) >= 24 -> no clip needed
        muv = (muA[w][l] + muA[w + 4][l]) / (muC[w][l] + muC[w + 4][l] + (float)L_P);

    const float wxd = Wx_dec[l * N_F + l];
    const float bxn = bx_dec[l];

    // ---- gate consts for this lane's hidden col ----
    const int hc = w * 16 + lm;
    float S = 0.0f;
    {
        const float4* wh4 = (const float4*)(Wh_dec + hc * N_F);
#pragma unroll
        for (int i = 0; i < 16; ++i) { float4 u = wh4[i]; S += u.x + u.y + u.z + u.w; }
    }
    const float bhv = bh_dec[hc];
    const float bR  = b_ih[hc] + b_hh[hc];
    const float bZ  = b_ih[H_DIM + hc] + b_hh[H_DIM + hc];
    const float bN  = b_ih[2 * H_DIM + hc];
    const float bG  = b_hh[2 * H_DIM + hc];

    // ---- weight B-fragments (float4 loads; persistent registers) ----
    // K layout: k<64 -> x_in (W_ih[:, :64]); 64<=k<128 -> m (W_ih[:, 192:]);
    // k>=128 -> h (W_ih[:, 64:192], +W_hh for r,z; W_hh n-part in wG).
    f16x8 wR[8], wZ[8], wN[8], wG[4];
#pragma unroll
    for (int fi = 0; fi < 8; ++fi) {
        const int kk = fi * 32 + quad * 8;
        const int jr = hc, jz = H_DIM + hc, jn = 2 * H_DIM + hc;
        F8 r8, z8, n8;
        if (fi < 2) {
            r8 = ld8(W_ih + jr * 256 + kk);
            z8 = ld8(W_ih + jz * 256 + kk);
            n8 = ld8(W_ih + jn * 256 + kk);
        } else if (fi < 4) {
            r8 = ld8(W_ih + jr * 256 + 128 + kk);  // col 192+(kk-64)
            z8 = ld8(W_ih + jz * 256 + 128 + kk);
            n8 = ld8(W_ih + jn * 256 + 128 + kk);
        } else {
            const int c = kk - 128;
            r8 = ld8(W_ih + jr * 256 + 64 + c);
            z8 = ld8(W_ih + jz * 256 + 64 + c);
            n8 = ld8(W_ih + jn * 256 + 64 + c);
            F8 rh = ld8(W_hh + jr * 128 + c);
            F8 zh = ld8(W_hh + jz * 128 + c);
            F8 g8 = ld8(W_hh + jn * 128 + c);
#pragma unroll
            for (int q = 0; q < 8; ++q) {
                r8.v[q] += rh.v[q];
                z8.v[q] += zh.v[q];
                wG[fi - 4][q] = (_Float16)g8.v[q];
            }
        }
#pragma unroll
        for (int q = 0; q < 8; ++q) {
            wR[fi][q] = (_Float16)r8.v[q];
            wZ[fi][q] = (_Float16)z8.v[q];
            wN[fi][q] = (_Float16)n8.v[q];
        }
    }

    // ---- projection weights (waves 4-7, 16 out cols each) ----
    f16x8 wP[4];
    float bpv = 0.0f;
    const int pn = (w & 3) * 16 + lm;
    if (w >= 4) {
        bpv = bp[pn];
#pragma unroll
        for (int p = 0; p < 4; ++p) {
            F8 p8 = ld8(Wp + pn * H_DIM + p * 32 + quad * 8);
#pragma unroll
            for (int q = 0; q < 8; ++q) wP[p][q] = (_Float16)p8.v[q];
        }
    }

    // ---- init V[0] for t=0 (dt=0, h=0 already zeroed) ----
    if (w < 4) {
        const size_t o = (size_t)(b0 + w) * L_H * N_F + l;
        float x0 = X[o], m0 = mask[o];
        const float gx = expnr_fast(bxn);
        float xi = (m0 != 0.0f) ? x0 : (x0 - muv) * gx + muv;
        V[0][4 * w * VROW + l]      = (_Float16)xi;
        V[0][4 * w * VROW + 64 + l] = (_Float16)m0;
    }

    float h = 0.0f;
    __syncthreads();

    auto ldxm = [&](int t, float& px, float& pm) {
        if (t < L_H) {
            const size_t o = (size_t)(b0 + w) * L_H * N_F + (size_t)t * N_F + l;
            px = X[o]; pm = mask[o];
        } else { px = 0.0f; pm = 0.0f; }
    };

    auto body = [&](int t, float cx, float cm, float& fx, float& fm) {
        const int p = t & 1;

        // A-fragments from V[p]
        f16x8 af[8];
#pragma unroll
        for (int fi = 0; fi < 8; ++fi)
            af[fi] = *(const f16x8*)&V[p][lm * VROW + fi * 32 + quad * 8];

        // global prefetch for step t+3 (waves 0-3)
        if (w < 4) ldxm(t + 3, fx, fm);

        // MFMAs (biases pre-folded into accumulator init)
        f32x4 aR = {bR, bR, bR, bR}, aZ = {bZ, bZ, bZ, bZ};
        f32x4 aN = {bN, bN, bN, bN}, aG = {bG, bG, bG, bG};
#pragma unroll
        for (int fi = 0; fi < 8; ++fi) {
            aR = __builtin_amdgcn_mfma_f32_16x16x32_f16(af[fi], wR[fi], aR, 0, 0, 0);
            aZ = __builtin_amdgcn_mfma_f32_16x16x32_f16(af[fi], wZ[fi], aZ, 0, 0, 0);
            aN = __builtin_amdgcn_mfma_f32_16x16x32_f16(af[fi], wN[fi], aN, 0, 0, 0);
        }
#pragma unroll
        for (int p4 = 0; p4 < 4; ++p4)
            aG = __builtin_amdgcn_mfma_f32_16x16x32_f16(af[4 + p4], wG[p4], aG, 0, 0, 0);

        // tail projection (waves 4-7; rep_t = decayed h = af[4..7])
        if (t >= L_H && w >= 4) {
            f32x4 aP = {bpv, bpv, bpv, bpv};
#pragma unroll
            for (int p4 = 0; p4 < 4; ++p4)
                aP = __builtin_amdgcn_mfma_f32_16x16x32_f16(af[4 + p4], wP[p4], aP, 0, 0, 0);
            out[((size_t)(b0 + quad) * L_P + (t - L_H)) * N_F + pn] = aP[0];
        }

        // stage next V x/m (waves 0-3) + gh for t+1 (all lanes) — off the chain
        float ghn = 0.0f;
        if (t < L_ALL - 1) {
            if (w < 4) {
                const float d  = dt_lds[(t + 1) * 4 + w];
                const float gx = expnr_fast(d * wxd + bxn);
                const float xi = (cm != 0.0f) ? cx : (cx - muv) * gx + muv;
                V[p ^ 1][4 * w * VROW + l]      = (_Float16)xi;
                V[p ^ 1][4 * w * VROW + 64 + l] = (_Float16)cm;
            }
            const float dq = dt_lds[(t + 1) * 4 + quad];
            ghn = expnr_fast(dq * S + bhv);
        }

        // gate triple (C/D reg 0 only: tile row 4*quad = batch b0+quad)
        {
            const float rg = sig_fast(aR[0]);
            const float zg = sig_fast(aZ[0]);
            const float ng = tanh_fast(aN[0] + rg * aG[0]);
            h = zg * (h - ng) + ng;
        }
        if (t < L_ALL - 1) {
            h *= ghn;  // decayed h = rep_{t+1}
            V[p ^ 1][4 * quad * VROW + H_DIM + hc] = (_Float16)h;
        }

        barrier_lds_only();
    };

    float aXv = 0, aMv = 0, bXv = 0, bMv = 0;
    if (w < 4) { ldxm(1, aXv, aMv); ldxm(2, bXv, bMv); }

    for (int t = 0; t < L_ALL; t += 2) {
        body(t,     aXv, aMv, aXv, aMv);
        body(t + 1, bXv, bMv, bXv, bMv);
    }
}

extern "C" void kernel_launch(void* const* d_in, const int* in_sizes, int n_in,
                              void* d_out, int out_size, void* d_ws, size_t ws_size,
                              hipStream_t stream) {
    const float* tp_pred = (const float*)d_in[0];
    const float* X       = (const float*)d_in[1];
    const float* tp_true = (const float*)d_in[2];
    const float* mask    = (const float*)d_in[3];
    const float* Wh_dec  = (const float*)d_in[4];
    const float* bh_dec  = (const float*)d_in[5];
    const float* Wx_dec  = (const float*)d_in[6];
    const float* bx_dec  = (const float*)d_in[7];
    const float* W_ih    = (const float*)d_in[8];
    const float* W_hh    = (const float*)d_in[9];
    const float* b_ih    = (const float*)d_in[10];
    const float* b_hh    = (const float*)d_in[11];
    const float* Wp      = (const float*)d_in[12];
    const float* bp      = (const float*)d_in[13];

    grud_kernel<<<dim3(B_SZ / 4), dim3(512), 0, stream>>>(
        tp_pred, X, tp_true, mask, Wh_dec, bh_dec, Wx_dec, bx_dec,
        W_ih, W_hh, b_ih, b_hh, Wp, bp, (float*)d_out);
}

// Round 4
// 232.529 us; speedup vs baseline: 1.6118x; 1.0475x over previous
//
#include <hip/hip_runtime.h>

#define L2E 1.4426950408889634f

typedef _Float16 f16x8 __attribute__((ext_vector_type(8)));
typedef _Float16 f16x4 __attribute__((ext_vector_type(4)));
typedef float f32x4 __attribute__((ext_vector_type(4)));

__device__ __forceinline__ float sig_fast(float x) {
    return __builtin_amdgcn_rcpf(1.0f + __builtin_amdgcn_exp2f(-L2E * x));
}
__device__ __forceinline__ float tanh_fast(float x) {
    return 1.0f - 2.0f * __builtin_amdgcn_rcpf(1.0f + __builtin_amdgcn_exp2f(2.0f * L2E * x));
}
__device__ __forceinline__ float expnr_fast(float x) {  // exp(-relu(x))
    return __builtin_amdgcn_exp2f(-L2E * fmaxf(x, 0.0f));
}
// Orders LDS only; global loads/stores stay in flight across the barrier.
__device__ __forceinline__ void barrier_lds_only() {
    __asm__ volatile("s_waitcnt lgkmcnt(0)\n\ts_barrier" ::: "memory");
}

struct F8 { float v[8]; };
__device__ __forceinline__ F8 ld8(const float* p) {
    F8 r;
    float4 a = *(const float4*)p, b = *(const float4*)(p + 4);
    r.v[0]=a.x; r.v[1]=a.y; r.v[2]=a.z; r.v[3]=a.w;
    r.v[4]=b.x; r.v[5]=b.y; r.v[6]=b.z; r.v[7]=b.w;
    return r;
}
__device__ __forceinline__ f16x8 cvt8(F8 a) {
    f16x8 r;
#pragma unroll
    for (int q = 0; q < 8; ++q) r[q] = (_Float16)a.v[q];
    return r;
}
__device__ __forceinline__ f16x8 cvt8s(F8 a, F8 b) {
    f16x8 r;
#pragma unroll
    for (int q = 0; q < 8; ++q) r[q] = (_Float16)(a.v[q] + b.v[q]);
    return r;
}

// 256 blocks x 4 batch rows (tile rows {0,4,8,12} -> C/D reg 0), 4 waves.
// Wave w owns hidden cols [32w, 32w+32) (2 MFMA col-tiles).
// The x/m half of the gate GEMM (K=128, h-independent) is produced ~8 steps
// ahead by an in-block MFMA pipeline into a 16-slot LDS ring; the serial
// recurrence consumes it and only MFMAs the h-part (K=128).
__global__ __launch_bounds__(256, 1) void grud_kernel(
    const float* __restrict__ tp_pred, const float* __restrict__ X,
    const float* __restrict__ tp_true, const float* __restrict__ mask,
    const float* __restrict__ Wh_dec, const float* __restrict__ bh_dec,
    const float* __restrict__ Wx_dec, const float* __restrict__ bx_dec,
    const float* __restrict__ W_ih, const float* __restrict__ W_hh,
    const float* __restrict__ b_ih, const float* __restrict__ b_hh,
    const float* __restrict__ Wp, const float* __restrict__ bp,
    float* __restrict__ out)
{
    constexpr int SR = 136;  // row stride (halfs): 128 + 8 pad
    __shared__ alignas(16) _Float16 ring[16 * 1536];   // [slot t&15][g][col][b] 49.2KB
    __shared__ alignas(16) _Float16 V[2][16 * SR];     // h A-tiles (rows {0,4,8,12} live)
    __shared__ alignas(16) _Float16 Astage[2][16 * SR];// producer x_in/m A-tiles
    __shared__ float dt_lds[480];                      // [t][b]
    __shared__ float mu_l[4][64];
    __shared__ float wxl[64], bxl[64];
    __shared__ char occupancy_pad[32768];              // force 1 block/CU (LDS > 80KB)

    const int tid  = threadIdx.x;
    const int w    = tid >> 6, l = tid & 63, quad = l >> 4, lm = l & 15;
    const int b0   = blockIdx.x * 4;

    if (tid > 100000) occupancy_pad[0] = 1;  // opaque keep-alive for pad

    // zero V (invalid tile rows must stay 0 forever)
    for (int i = tid; i < 16 * SR; i += 256) ((unsigned*)V)[i] = 0;

    // dt
    for (int i = tid; i < 480; i += 256) {
        int t = i >> 2, q = i & 3, b = b0 + q;
        float v = 0.0f;
        if (t) {
            float cur = (t < 96) ? tp_true[b * 96 + t] : tp_pred[b * 24 + t - 96];
            float prv = (t - 1 < 96) ? tp_true[b * 96 + t - 1] : tp_pred[b * 24 + t - 97];
            v = cur - prv;
        }
        dt_lds[i] = v;
    }
    if (tid < 64) { wxl[tid] = Wx_dec[tid * 65]; bxl[tid] = bx_dec[tid]; }

    // mu: wave w -> batch w, lane l -> feature l
    {
        const float* xr = X    + ((size_t)(b0 + w) * 96) * 64 + l;
        const float* mr = mask + ((size_t)(b0 + w) * 96) * 64 + l;
        float a = 0.0f, c = 0.0f;
#pragma unroll 4
        for (int t = 0; t < 96; ++t) {
            float x = xr[t * 64], m = mr[t * 64];
            a += x * (1.0f - m); c += 1.0f - m;
        }
        mu_l[w][l] = a / (c + 24.0f);  // cnt = sum(1-m) + 24 (pred window) >= 24
    }

    const int c0 = 32 * w + lm, c1 = c0 + 16;

    // producer B-frags: W_xm (k<64 -> W_ih[:, :64]; k>=64 -> W_ih[:, 192:])
    f16x8 wxf[3][2][4];
#pragma unroll
    for (int g = 0; g < 3; ++g)
#pragma unroll
        for (int j = 0; j < 2; ++j)
#pragma unroll
            for (int fi = 0; fi < 4; ++fi) {
                const int row = g * 128 + (j ? c1 : c0);
                const int k0 = fi * 32 + quad * 8;
                wxf[g][j][fi] = cvt8(ld8(W_ih + row * 256 + (k0 < 64 ? k0 : 128 + k0)));
            }

    // consumer B-frags: h-part (W_ih cols 64..191; +W_hh folded for r,z)
    f16x8 wRZ[2][2][4], wNf[2][4], wGf[2][4], wPf[4];
    float S_[2], bh_[2], bR_[2], bZ_[2], bN_[2], bG_[2];
#pragma unroll
    for (int j = 0; j < 2; ++j) {
        const int c = j ? c1 : c0;
#pragma unroll
        for (int fi = 0; fi < 4; ++fi) {
            const int k0 = fi * 32 + quad * 8;
            wRZ[0][j][fi] = cvt8s(ld8(W_ih + c * 256 + 64 + k0),
                                  ld8(W_hh + c * 128 + k0));
            wRZ[1][j][fi] = cvt8s(ld8(W_ih + (128 + c) * 256 + 64 + k0),
                                  ld8(W_hh + (128 + c) * 128 + k0));
            wNf[j][fi] = cvt8(ld8(W_ih + (256 + c) * 256 + 64 + k0));
            wGf[j][fi] = cvt8(ld8(W_hh + (256 + c) * 128 + k0));
        }
        float s = 0.0f;
        const float4* wh4 = (const float4*)(Wh_dec + c * 64);
#pragma unroll
        for (int i = 0; i < 16; ++i) { float4 u = wh4[i]; s += u.x + u.y + u.z + u.w; }
        S_[j]  = s;
        bh_[j] = bh_dec[c];
        bR_[j] = b_ih[c] + b_hh[c];
        bZ_[j] = b_ih[128 + c] + b_hh[128 + c];
        bN_[j] = b_ih[256 + c];
        bG_[j] = b_hh[256 + c];
    }
    const int pn = w * 16 + lm;
    const float bpv = bp[pn];
#pragma unroll
    for (int fi = 0; fi < 4; ++fi)
        wPf[fi] = cvt8(ld8(Wp + pn * 128 + fi * 32 + quad * 8));

    // ---- producer pipeline stages ----
    auto prodLoad = [&](int gp, float4& px, float4& pm) {
        if (gp >= 24) { px = make_float4(0,0,0,0); pm = make_float4(0,0,0,0); return; }
        const int R = tid >> 4, tg = 4 * gp + (R >> 2), b = R & 3;
        const size_t o = (((size_t)(b0 + b) * 96) + tg) * 64 + (tid & 15) * 4;
        px = *(const float4*)(X + o);
        pm = *(const float4*)(mask + o);
    };
    auto prodStage = [&](int gp, float4 px, float4 pm) {
        const int R = tid >> 4, toff = R >> 2, b = R & 3;
        const int tg = 4 * gp + toff, n0 = (tid & 15) * 4;
        const float d = dt_lds[tg * 4 + b];
        const float xs[4] = {px.x, px.y, px.z, px.w};
        const float ms[4] = {pm.x, pm.y, pm.z, pm.w};
        f16x4 xi, mm;
#pragma unroll
        for (int e = 0; e < 4; ++e) {
            const int n = n0 + e;
            const float gxv = expnr_fast(d * wxl[n] + bxl[n]);
            const float muv = mu_l[b][n];
            float v;
            if (gp < 24) {  // LOCF collapse: m==0 -> X_locf == x_t
                v = (ms[e] != 0.0f) ? xs[e] : (xs[e] - muv) * gxv + muv;
                mm[e] = (_Float16)ms[e];
            } else {        // t>=96: x=0,m=0 -> x_in = (1-gx)*mu
                v = (1.0f - gxv) * muv;
                mm[e] = (_Float16)0.0f;
            }
            xi[e] = (_Float16)v;
        }
        *(f16x4*)&Astage[gp & 1][R * SR + n0]      = xi;
        *(f16x4*)&Astage[gp & 1][R * SR + 64 + n0] = mm;
    };
    auto prodMMA = [&](int gp, int j) {
        f16x8 ap[4];
#pragma unroll
        for (int fi = 0; fi < 4; ++fi)
            ap[fi] = *(const f16x8*)&Astage[gp & 1][lm * SR + fi * 32 + quad * 8];
        const int tg = 4 * gp + quad, slot = tg & 15;
        const int c = j ? c1 : c0;
#pragma unroll
        for (int g = 0; g < 3; ++g) {
            f32x4 acc = {0, 0, 0, 0};
#pragma unroll
            for (int fi = 0; fi < 4; ++fi)
                acc = __builtin_amdgcn_mfma_f32_16x16x32_f16(ap[fi], wxf[g][j][fi], acc, 0, 0, 0);
            f16x4 pk = {(_Float16)acc[0], (_Float16)acc[1], (_Float16)acc[2], (_Float16)acc[3]};
            *(f16x4*)&ring[slot * 1536 + (g * 128 + c) * 4] = pk;
        }
    };

    float h0 = 0.0f, h1 = 0.0f;

    // ---- serial step (consumer) ----
    auto step = [&](int t, auto&& extra) {
        const int p = t & 1;
        f16x8 af[4];
#pragma unroll
        for (int fi = 0; fi < 4; ++fi)
            af[fi] = *(const f16x8*)&V[p][lm * SR + fi * 32 + quad * 8];
        const int slot = t & 15;
        _Float16 g6[6];
#pragma unroll
        for (int j = 0; j < 2; ++j)
#pragma unroll
            for (int g = 0; g < 3; ++g)
                g6[j * 3 + g] = ring[slot * 1536 + (g * 128 + (j ? c1 : c0)) * 4 + quad];

        extra();  // this step's slice of producer work

        f32x4 aR0 = {(float)g6[0] + bR_[0], 0, 0, 0}, aZ0 = {(float)g6[1] + bZ_[0], 0, 0, 0};
        f32x4 aN0 = {(float)g6[2] + bN_[0], 0, 0, 0}, aG0 = {bG_[0], 0, 0, 0};
        f32x4 aR1 = {(float)g6[3] + bR_[1], 0, 0, 0}, aZ1 = {(float)g6[4] + bZ_[1], 0, 0, 0};
        f32x4 aN1 = {(float)g6[5] + bN_[1], 0, 0, 0}, aG1 = {bG_[1], 0, 0, 0};
#pragma unroll
        for (int fi = 0; fi < 4; ++fi) {
            aR0 = __builtin_amdgcn_mfma_f32_16x16x32_f16(af[fi], wRZ[0][0][fi], aR0, 0, 0, 0);
            aZ0 = __builtin_amdgcn_mfma_f32_16x16x32_f16(af[fi], wRZ[1][0][fi], aZ0, 0, 0, 0);
            aN0 = __builtin_amdgcn_mfma_f32_16x16x32_f16(af[fi], wNf[0][fi], aN0, 0, 0, 0);
            aG0 = __builtin_amdgcn_mfma_f32_16x16x32_f16(af[fi], wGf[0][fi], aG0, 0, 0, 0);
            aR1 = __builtin_amdgcn_mfma_f32_16x16x32_f16(af[fi], wRZ[0][1][fi], aR1, 0, 0, 0);
            aZ1 = __builtin_amdgcn_mfma_f32_16x16x32_f16(af[fi], wRZ[1][1][fi], aZ1, 0, 0, 0);
            aN1 = __builtin_amdgcn_mfma_f32_16x16x32_f16(af[fi], wNf[1][fi], aN1, 0, 0, 0);
            aG1 = __builtin_amdgcn_mfma_f32_16x16x32_f16(af[fi], wGf[1][fi], aG1, 0, 0, 0);
        }
        if (t >= 96) {  // rep_t = decayed h = af
            f32x4 aP = {bpv, 0, 0, 0};
#pragma unroll
            for (int fi = 0; fi < 4; ++fi)
                aP = __builtin_amdgcn_mfma_f32_16x16x32_f16(af[fi], wPf[fi], aP, 0, 0, 0);
            out[((size_t)(b0 + quad) * 24 + (t - 96)) * 64 + pn] = aP[0];
        }
        {
            const float rg0 = sig_fast(aR0[0]), zg0 = sig_fast(aZ0[0]);
            const float ng0 = tanh_fast(aN0[0] + rg0 * aG0[0]);
            h0 = zg0 * (h0 - ng0) + ng0;
            const float rg1 = sig_fast(aR1[0]), zg1 = sig_fast(aZ1[0]);
            const float ng1 = tanh_fast(aN1[0] + rg1 * aG1[0]);
            h1 = zg1 * (h1 - ng1) + ng1;
        }
        if (t < 119) {
            const float d = dt_lds[(t + 1) * 4 + quad];
            h0 *= expnr_fast(d * S_[0] + bh_[0]);  // decayed h = rep_{t+1}
            h1 *= expnr_fast(d * S_[1] + bh_[1]);
            V[p ^ 1][(4 * quad) * SR + c0] = (_Float16)h0;
            V[p ^ 1][(4 * quad) * SR + c1] = (_Float16)h1;
        }
        barrier_lds_only();
    };

    // ---- preamble: produce granules 0,1 (ring slots t=0..7) ----
    {
        float4 px0, pm0, px1, pm1;
        prodLoad(0, px0, pm0);
        prodLoad(1, px1, pm1);
        __syncthreads();  // dt/mu/wxl/V-zero ready
        prodStage(0, px0, pm0);
        prodStage(1, px1, pm1);
        __syncthreads();
        prodMMA(0, 0); prodMMA(0, 1);
        prodMMA(1, 0); prodMMA(1, 1);
        barrier_lds_only();
    }

    // ---- main loop: 30 groups of 4 steps; group k produces granule k+2 ----
    for (int k = 0; k < 30; ++k) {
        const int gp = k + 2;
        float4 px, pm;
        step(4 * k + 0, [&] { if (gp < 30) prodLoad(gp, px, pm); });
        step(4 * k + 1, [&] { if (gp < 30) prodStage(gp, px, pm); });
        step(4 * k + 2, [&] { if (gp < 30) prodMMA(gp, 0); });
        step(4 * k + 3, [&] { if (gp < 30) prodMMA(gp, 1); });
    }
}

extern "C" void kernel_launch(void* const* d_in, const int* in_sizes, int n_in,
                              void* d_out, int out_size, void* d_ws, size_t ws_size,
                              hipStream_t stream) {
    const float* tp_pred = (const float*)d_in[0];
    const float* X       = (const float*)d_in[1];
    const float* tp_true = (const float*)d_in[2];
    const float* mask    = (const float*)d_in[3];
    const float* Wh_dec  = (const float*)d_in[4];
    const float* bh_dec  = (const float*)d_in[5];
    const float* Wx_dec  = (const float*)d_in[6];
    const float* bx_dec  = (const float*)d_in[7];
    const float* W_ih    = (const float*)d_in[8];
    const float* W_hh    = (const float*)d_in[9];
    const float* b_ih    = (const float*)d_in[10];
    const float* b_hh    = (const float*)d_in[11];
    const float* Wp      = (const float*)d_in[12];
    const float* bp      = (const float*)d_in[13];

    grud_kernel<<<dim3(256), dim3(256), 0, stream>>>(
        tp_pred, X, tp_true, mask, Wh_dec, bh_dec, Wx_dec, bx_dec,
        W_ih, W_hh, b_ih, b_hh, Wp, bp, (float*)d_out);
}

// Round 5
// 204.119 us; speedup vs baseline: 1.8362x; 1.1392x over previous
//
#include <hip/hip_runtime.h>

#define L2E 1.4426950408889634f

typedef _Float16 f16x8 __attribute__((ext_vector_type(8)));
typedef _Float16 f16x4 __attribute__((ext_vector_type(4)));
typedef float f32x4 __attribute__((ext_vector_type(4)));

__device__ __forceinline__ float sig_fast(float x) {
    return __builtin_amdgcn_rcpf(1.0f + __builtin_amdgcn_exp2f(-L2E * x));
}
__device__ __forceinline__ float tanh_fast(float x) {
    return 1.0f - 2.0f * __builtin_amdgcn_rcpf(1.0f + __builtin_amdgcn_exp2f(2.0f * L2E * x));
}
__device__ __forceinline__ float expnr_fast(float x) {  // exp(-relu(x))
    return __builtin_amdgcn_exp2f(-L2E * fmaxf(x, 0.0f));
}
// Orders LDS only; global loads/stores stay in flight across the barrier.
__device__ __forceinline__ void barrier_lds_only() {
    __asm__ volatile("s_waitcnt lgkmcnt(0)\n\ts_barrier" ::: "memory");
}

struct F8 { float v[8]; };
__device__ __forceinline__ F8 ld8(const float* p) {
    F8 r;
    float4 a = *(const float4*)p, b = *(const float4*)(p + 4);
    r.v[0]=a.x; r.v[1]=a.y; r.v[2]=a.z; r.v[3]=a.w;
    r.v[4]=b.x; r.v[5]=b.y; r.v[6]=b.z; r.v[7]=b.w;
    return r;
}
__device__ __forceinline__ f16x8 cvt8(F8 a) {
    f16x8 r;
#pragma unroll
    for (int q = 0; q < 8; ++q) r[q] = (_Float16)a.v[q];
    return r;
}
__device__ __forceinline__ f16x8 cvt8s(F8 a, F8 b) {
    f16x8 r;
#pragma unroll
    for (int q = 0; q < 8; ++q) r[q] = (_Float16)(a.v[q] + b.v[q]);
    return r;
}

// 256 blocks x 4 batch rows, 512 threads = 8 waves, wave-specialized:
//   waves 0-3 (consumers): serial GRU recurrence, h-part GEMM (K=128) only.
//     Wave w owns hidden cols [32w,32w+32); gates fully in-register.
//   waves 4-7 (producers): x/m-part GEMM (K=128, h-independent) one granule
//     (4 timesteps) ahead into an 8-slot LDS ring + the tail projection.
// 1 consumer + 1 producer wave per SIMD -> co-scheduled issue overlap (m114).
// Ring layout [slot][col][batch][gate(r,z,n,pad)] -> both sides use b64 ops.
__global__ __launch_bounds__(512, 2) void grud_kernel(
    const float* __restrict__ tp_pred, const float* __restrict__ X,
    const float* __restrict__ tp_true, const float* __restrict__ mask,
    const float* __restrict__ Wh_dec, const float* __restrict__ bh_dec,
    const float* __restrict__ Wx_dec, const float* __restrict__ bx_dec,
    const float* __restrict__ W_ih, const float* __restrict__ W_hh,
    const float* __restrict__ b_ih, const float* __restrict__ b_hh,
    const float* __restrict__ Wp, const float* __restrict__ bp,
    float* __restrict__ out)
{
    constexpr int SR = 136;  // A-tile row stride (halfs): 128 + 8 pad
    __shared__ alignas(16) _Float16 ring[8 * 2048];  // [slot][c*16+b*4+g] 32KB
    __shared__ alignas(16) _Float16 V[2][16 * SR];   // h A-tiles (rows {0,4,8,12} live)
    __shared__ alignas(16) _Float16 Astage[16 * SR]; // producer x_in/m A-tile
    __shared__ float dt_lds[480];                    // [t][b]
    __shared__ float mu_l[4][64];
    __shared__ float wxl[64], bxl[64];
    __shared__ char occ_pad[34000];                  // force 1 block/CU (LDS > 80KB)

    const int tid  = threadIdx.x;
    const int w    = tid >> 6, l = tid & 63, quad = l >> 4, lm = l & 15;
    const int b0   = blockIdx.x * 4;

    if (tid > 100000) occ_pad[0] = 1;  // opaque keep-alive for pad

    // zero V (invalid tile rows must stay 0 forever)
    for (int i = tid; i < 16 * SR; i += 512) ((unsigned*)V)[i] = 0;

    // dt
    if (tid < 480) {
        int t = tid >> 2, q = tid & 3, b = b0 + q;
        float v = 0.0f;
        if (t) {
            float cur = (t < 96) ? tp_true[b * 96 + t] : tp_pred[b * 24 + t - 96];
            float prv = (t - 1 < 96) ? tp_true[b * 96 + t - 1] : tp_pred[b * 24 + t - 97];
            v = cur - prv;
        }
        dt_lds[tid] = v;
    }
    if (tid < 64) { wxl[tid] = Wx_dec[tid * 65]; bxl[tid] = bx_dec[tid]; }

    if (w >= 4) {
        // ========================= PRODUCER WAVES =========================
        const int pw   = w - 4;          // 0..3
        const int ptid = tid - 256;      // 0..255
        const int c0   = 32 * pw + lm, c1 = c0 + 16;

        // mu for batch pw (lane l -> feature l)
        {
            const float* xr = X    + ((size_t)(b0 + pw) * 96) * 64 + l;
            const float* mr = mask + ((size_t)(b0 + pw) * 96) * 64 + l;
            float a = 0.0f, c = 0.0f;
#pragma unroll 4
            for (int t = 0; t < 96; ++t) {
                float x = xr[t * 64], m = mr[t * 64];
                a += x * (1.0f - m); c += 1.0f - m;
            }
            mu_l[pw][l] = a / (c + 24.0f);  // cnt = sum(1-m) + 24 >= 24, no clip
        }

        // x/m-part B-frags: k<64 -> W_ih[:, :64]; k>=64 -> W_ih[:, 192:]
        f16x8 wxf[3][2][4];
#pragma unroll
        for (int g = 0; g < 3; ++g)
#pragma unroll
            for (int j = 0; j < 2; ++j)
#pragma unroll
                for (int fi = 0; fi < 4; ++fi) {
                    const int row = g * 128 + (j ? c1 : c0);
                    const int k0 = fi * 32 + quad * 8;
                    wxf[g][j][fi] = cvt8(ld8(W_ih + row * 256 + (k0 < 64 ? k0 : 128 + k0)));
                }

        // projection weights (this wave covers out cols pn)
        const int pn = pw * 16 + lm;
        const float bpv = bp[pn];
        f16x8 wPf[4];
#pragma unroll
        for (int fi = 0; fi < 4; ++fi)
            wPf[fi] = cvt8(ld8(Wp + pn * 128 + fi * 32 + quad * 8));

        auto prodLoad = [&](int gp, float4& px, float4& pm) {
            if (gp >= 24) { px = make_float4(0,0,0,0); pm = make_float4(0,0,0,0); return; }
            const int R = ptid >> 4, tg = 4 * gp + (R >> 2), b = R & 3;
            const size_t o = (((size_t)(b0 + b) * 96) + tg) * 64 + (ptid & 15) * 4;
            px = *(const float4*)(X + o);
            pm = *(const float4*)(mask + o);
        };
        auto prodStage = [&](int gp, float4 px, float4 pm) {
            const int R = ptid >> 4, toff = R >> 2, b = R & 3;
            const int tg = 4 * gp + toff, n0 = (ptid & 15) * 4;
            const float d = dt_lds[tg * 4 + b];
            const float xs[4] = {px.x, px.y, px.z, px.w};
            const float ms[4] = {pm.x, pm.y, pm.z, pm.w};
            f16x4 xi, mm;
#pragma unroll
            for (int e = 0; e < 4; ++e) {
                const int n = n0 + e;
                const float gxv = expnr_fast(d * wxl[n] + bxl[n]);
                const float muv = mu_l[b][n];
                float v;
                if (gp < 24) {  // LOCF collapse: m==0 -> X_locf == x_t
                    v = (ms[e] != 0.0f) ? xs[e] : (xs[e] - muv) * gxv + muv;
                    mm[e] = (_Float16)ms[e];
                } else {        // t>=96: x=0,m=0 -> x_in = (1-gx)*mu
                    v = (1.0f - gxv) * muv;
                    mm[e] = (_Float16)0.0f;
                }
                xi[e] = (_Float16)v;
            }
            *(f16x4*)&Astage[R * SR + n0]      = xi;
            *(f16x4*)&Astage[R * SR + 64 + n0] = mm;
        };
        auto prodMMA = [&](int gp, int j) {
            f16x8 ap[4];
#pragma unroll
            for (int fi = 0; fi < 4; ++fi)
                ap[fi] = *(const f16x8*)&Astage[lm * SR + fi * 32 + quad * 8];
            const int c = j ? c1 : c0;
            const int slot = (4 * gp + quad) & 7;  // this lane's quad = time offset
            f32x4 aR = {0,0,0,0}, aZ = {0,0,0,0}, aN = {0,0,0,0};
#pragma unroll
            for (int fi = 0; fi < 4; ++fi) {
                aR = __builtin_amdgcn_mfma_f32_16x16x32_f16(ap[fi], wxf[0][j][fi], aR, 0, 0, 0);
                aZ = __builtin_amdgcn_mfma_f32_16x16x32_f16(ap[fi], wxf[1][j][fi], aZ, 0, 0, 0);
                aN = __builtin_amdgcn_mfma_f32_16x16x32_f16(ap[fi], wxf[2][j][fi], aN, 0, 0, 0);
            }
#pragma unroll
            for (int rb = 0; rb < 4; ++rb) {  // rb = batch (C/D reg)
                f16x4 pk = {(_Float16)aR[rb], (_Float16)aZ[rb], (_Float16)aN[rb], (_Float16)0.0f};
                *(f16x4*)&ring[slot * 2048 + c * 16 + rb * 4] = pk;
            }
        };

        __syncthreads();  // #1: mu/dt/wxl/V-zero visible
        {   // preamble: granule 0 (ring slots 0-3)
            float4 px, pm;
            prodLoad(0, px, pm);
            prodStage(0, px, pm);
            prodMMA(0, 0); prodMMA(0, 1);
        }
        __syncthreads();  // #2: granule 0 visible

        float4 px, pm;
        for (int t = 0; t < 120; ++t) {
            const int gp = (t >> 2) + 1, ph = t & 3;
            if (ph == 0)      { if (gp < 30) prodLoad(gp, px, pm); }
            else if (ph == 1) { if (gp < 30) prodStage(gp, px, pm); }
            else if (ph == 2) { if (gp < 30) prodMMA(gp, 0); }
            else              { if (gp < 30) prodMMA(gp, 1); }

            if (t >= 96) {  // projection: rep_t = decayed h = V[t&1] tile
                f16x8 af[4];
#pragma unroll
                for (int fi = 0; fi < 4; ++fi)
                    af[fi] = *(const f16x8*)&V[t & 1][lm * SR + fi * 32 + quad * 8];
                f32x4 aP = {bpv, 0, 0, 0};
#pragma unroll
                for (int fi = 0; fi < 4; ++fi)
                    aP = __builtin_amdgcn_mfma_f32_16x16x32_f16(af[fi], wPf[fi], aP, 0, 0, 0);
                out[((size_t)(b0 + quad) * 24 + (t - 96)) * 64 + pn] = aP[0];
            }
            barrier_lds_only();
        }
    } else {
        // ========================= CONSUMER WAVES =========================
        const int c0 = 32 * w + lm, c1 = c0 + 16;

        // h-part B-frags (W_ih cols 64..191; +W_hh folded for r,z)
        f16x8 wR[2][4], wZ[2][4], wN[2][4], wG[2][4];
        float S_[2], bh_[2], bR_[2], bZ_[2], bN_[2], bG_[2];
#pragma unroll
        for (int j = 0; j < 2; ++j) {
            const int c = j ? c1 : c0;
#pragma unroll
            for (int fi = 0; fi < 4; ++fi) {
                const int k0 = fi * 32 + quad * 8;
                wR[j][fi] = cvt8s(ld8(W_ih + c * 256 + 64 + k0),
                                  ld8(W_hh + c * 128 + k0));
                wZ[j][fi] = cvt8s(ld8(W_ih + (128 + c) * 256 + 64 + k0),
                                  ld8(W_hh + (128 + c) * 128 + k0));
                wN[j][fi] = cvt8(ld8(W_ih + (256 + c) * 256 + 64 + k0));
                wG[j][fi] = cvt8(ld8(W_hh + (256 + c) * 128 + k0));
            }
            float s = 0.0f;
            const float4* wh4 = (const float4*)(Wh_dec + c * 64);
#pragma unroll
            for (int i = 0; i < 16; ++i) { float4 u = wh4[i]; s += u.x + u.y + u.z + u.w; }
            S_[j]  = s;                       // dt @ Wh_dec.T = dt * rowsum
            bh_[j] = bh_dec[c];
            bR_[j] = b_ih[c] + b_hh[c];
            bZ_[j] = b_ih[128 + c] + b_hh[128 + c];
            bN_[j] = b_ih[256 + c];
            bG_[j] = b_hh[256 + c];
        }

        __syncthreads();  // #1 (pairs with producer's)
        __syncthreads();  // #2

        float h0 = 0.0f, h1 = 0.0f;
        for (int t = 0; t < 120; ++t) {
            const _Float16* Vp = V[t & 1];
            const int sb = (t & 7) * 2048;
            const f16x4 g0 = *(const f16x4*)&ring[sb + c0 * 16 + quad * 4];
            const f16x4 g1 = *(const f16x4*)&ring[sb + c1 * 16 + quad * 4];
            f16x8 af[4];
#pragma unroll
            for (int fi = 0; fi < 4; ++fi)
                af[fi] = *(const f16x8*)&Vp[lm * SR + fi * 32 + quad * 8];

            f32x4 aR0 = {(float)g0[0] + bR_[0], 0, 0, 0};
            f32x4 aZ0 = {(float)g0[1] + bZ_[0], 0, 0, 0};
            f32x4 aN0 = {(float)g0[2] + bN_[0], 0, 0, 0};
            f32x4 aG0 = {bG_[0], 0, 0, 0};
            f32x4 aR1 = {(float)g1[0] + bR_[1], 0, 0, 0};
            f32x4 aZ1 = {(float)g1[1] + bZ_[1], 0, 0, 0};
            f32x4 aN1 = {(float)g1[2] + bN_[1], 0, 0, 0};
            f32x4 aG1 = {bG_[1], 0, 0, 0};
#pragma unroll
            for (int fi = 0; fi < 4; ++fi) {
                aR0 = __builtin_amdgcn_mfma_f32_16x16x32_f16(af[fi], wR[0][fi], aR0, 0, 0, 0);
                aZ0 = __builtin_amdgcn_mfma_f32_16x16x32_f16(af[fi], wZ[0][fi], aZ0, 0, 0, 0);
                aN0 = __builtin_amdgcn_mfma_f32_16x16x32_f16(af[fi], wN[0][fi], aN0, 0, 0, 0);
                aG0 = __builtin_amdgcn_mfma_f32_16x16x32_f16(af[fi], wG[0][fi], aG0, 0, 0, 0);
                aR1 = __builtin_amdgcn_mfma_f32_16x16x32_f16(af[fi], wR[1][fi], aR1, 0, 0, 0);
                aZ1 = __builtin_amdgcn_mfma_f32_16x16x32_f16(af[fi], wZ[1][fi], aZ1, 0, 0, 0);
                aN1 = __builtin_amdgcn_mfma_f32_16x16x32_f16(af[fi], wN[1][fi], aN1, 0, 0, 0);
                aG1 = __builtin_amdgcn_mfma_f32_16x16x32_f16(af[fi], wG[1][fi], aG1, 0, 0, 0);
            }

            // gates (C/D reg 0: tile row 4*quad = batch b0+quad)
            {
                const float rg0 = sig_fast(aR0[0]), zg0 = sig_fast(aZ0[0]);
                const float ng0 = tanh_fast(aN0[0] + rg0 * aG0[0]);
                h0 = zg0 * (h0 - ng0) + ng0;
                const float rg1 = sig_fast(aR1[0]), zg1 = sig_fast(aZ1[0]);
                const float ng1 = tanh_fast(aN1[0] + rg1 * aG1[0]);
                h1 = zg1 * (h1 - ng1) + ng1;
            }
            if (t < 119) {
                const float d = dt_lds[(t + 1) * 4 + quad];
                h0 *= expnr_fast(d * S_[0] + bh_[0]);  // decayed h = rep_{t+1}
                h1 *= expnr_fast(d * S_[1] + bh_[1]);
                _Float16* Vn = V[(t & 1) ^ 1];
                Vn[(4 * quad) * SR + c0] = (_Float16)h0;
                Vn[(4 * quad) * SR + c1] = (_Float16)h1;
            }
            barrier_lds_only();
        }
    }
}

extern "C" void kernel_launch(void* const* d_in, const int* in_sizes, int n_in,
                              void* d_out, int out_size, void* d_ws, size_t ws_size,
                              hipStream_t stream) {
    const float* tp_pred = (const float*)d_in[0];
    const float* X       = (const float*)d_in[1];
    const float* tp_true = (const float*)d_in[2];
    const float* mask    = (const float*)d_in[3];
    const float* Wh_dec  = (const float*)d_in[4];
    const float* bh_dec  = (const float*)d_in[5];
    const float* Wx_dec  = (const float*)d_in[6];
    const float* bx_dec  = (const float*)d_in[7];
    const float* W_ih    = (const float*)d_in[8];
    const float* W_hh    = (const float*)d_in[9];
    const float* b_ih    = (const float*)d_in[10];
    const float* b_hh    = (const float*)d_in[11];
    const float* Wp      = (const float*)d_in[12];
    const float* bp      = (const float*)d_in[13];

    grud_kernel<<<dim3(256), dim3(512), 0, stream>>>(
        tp_pred, X, tp_true, mask, Wh_dec, bh_dec, Wx_dec, bx_dec,
        W_ih, W_hh, b_ih, b_hh, Wp, bp, (float*)d_out);
}